// Round 1
// baseline (841.013 us; speedup 1.0000x reference)
//
#include <hip/hip_runtime.h>
#include <hip/hip_bf16.h>
#include <math.h>

#define SLOPE 0.2f

// ---------------- CSR build ----------------

__global__ void deg_kernel(const int* __restrict__ dst, int* __restrict__ deg, int E) {
    int i = blockIdx.x * blockDim.x + threadIdx.x;
    if (i < E) atomicAdd(&deg[dst[i]], 1);
}

// single-block exclusive scan over N elements (N ~ 50000)
__global__ __launch_bounds__(1024) void scan_kernel(const int* __restrict__ deg,
                                                    int* __restrict__ offs, int n) {
    __shared__ int sums[1024];
    int t = threadIdx.x;
    int chunk = (n + 1023) >> 10;
    int beg = t * chunk;
    int end = beg + chunk; if (end > n) end = n;
    int s = 0;
    for (int i = beg; i < end && i >= 0; ++i) s += deg[i];
    sums[t] = s;
    __syncthreads();
    // Hillis-Steele inclusive scan
    for (int off = 1; off < 1024; off <<= 1) {
        int v = (t >= off) ? sums[t - off] : 0;
        __syncthreads();
        sums[t] += v;
        __syncthreads();
    }
    int run = (t == 0) ? 0 : sums[t - 1];
    for (int i = beg; i < end; ++i) { offs[i] = run; run += deg[i]; }
    if (t == 1023) offs[n] = run;   // == E
}

__global__ void fill_kernel(const int* __restrict__ src, const int* __restrict__ dst,
                            const int* __restrict__ offs, int* __restrict__ cursor,
                            int* __restrict__ csr_src, int E) {
    int i = blockIdx.x * blockDim.x + threadIdx.x;
    if (i < E) {
        int d = dst[i];
        int p = atomicAdd(&cursor[d], 1);
        csr_src[offs[d] + p] = src[i];
    }
}

// ---------------- GEMM (+ el/er epilogue) ----------------
// H_out[n, M] = X[n, K] @ W[K, M]; block = M threads, ROWS rows per block.
// Epilogue: el[n,h] = sum_d H[n,h,d]*AL[h,d]; er likewise (wave = head, D=64).
template <int K, int M, int ROWS, int H>
__global__ __launch_bounds__(M) void gemm_attn(const float* __restrict__ X,
                                               const float* __restrict__ W,
                                               const float* __restrict__ AL,
                                               const float* __restrict__ AR,
                                               float* __restrict__ Hout,
                                               float* __restrict__ el,
                                               float* __restrict__ er, int n) {
    __shared__ float xs[ROWS * K];
    const int tid = threadIdx.x;
    const int row0 = blockIdx.x * ROWS;
    for (int idx = tid; idx < ROWS * K; idx += M) {
        int r = idx / K, c = idx - r * K;
        int row = row0 + r;
        xs[idx] = (row < n) ? X[(long long)row * K + c] : 0.f;
    }
    __syncthreads();
    float acc[ROWS];
#pragma unroll
    for (int r = 0; r < ROWS; ++r) acc[r] = 0.f;
    for (int k = 0; k < K; ++k) {
        float wv = W[k * M + tid];
#pragma unroll
        for (int r = 0; r < ROWS; ++r) acc[r] += xs[r * K + k] * wv;
    }
    const int head = tid >> 6;
    const int lane = tid & 63;
    const float alv = AL[head * 64 + lane];
    const float arv = AR[head * 64 + lane];
#pragma unroll
    for (int r = 0; r < ROWS; ++r) {
        int row = row0 + r;
        if (row >= n) break;
        Hout[(long long)row * M + tid] = acc[r];
        float a = acc[r] * alv, b = acc[r] * arv;
#pragma unroll
        for (int s2 = 32; s2 > 0; s2 >>= 1) {
            a += __shfl_xor(a, s2, 64);
            b += __shfl_xor(b, s2, 64);
        }
        if (lane == 0) {
            el[row * H + head] = a;
            er[row * H + head] = b;
        }
    }
}

// ---------------- online-softmax gather-aggregate ----------------
// one wave per (node, head); lane = d in [0,64)
template <int H, int D, bool ELU>
__global__ __launch_bounds__(256) void aggr_kernel(const float* __restrict__ Hf,
                                                   const float* __restrict__ el,
                                                   const float* __restrict__ er,
                                                   const int* __restrict__ offs,
                                                   const int* __restrict__ csr_src,
                                                   const float* __restrict__ bias,
                                                   float* __restrict__ out, int n) {
    int wid = (blockIdx.x * blockDim.x + threadIdx.x) >> 6;
    int lane = threadIdx.x & 63;
    if (wid >= n * H) return;
    int node = wid / H;
    int head = wid - node * H;
    const float erv = er[node * H + head];
    int beg = offs[node], end = offs[node + 1];
    float m = -INFINITY, l = 0.f, acc = 0.f;
    for (int i = beg; i < end; ++i) {
        int s = csr_src[i];
        float e = el[s * H + head] + erv;
        e = (e > 0.f) ? e : SLOPE * e;
        float mn = fmaxf(m, e);
        float sc = __expf(m - mn);   // m=-inf first iter -> 0
        float p = __expf(e - mn);
        float hv = Hf[((long long)s * H + head) * D + lane];
        l = l * sc + p;
        acc = acc * sc + p * hv;
        m = mn;
    }
    float v = (l > 0.f) ? acc / l : 0.f;
    v += bias[head * D + lane];
    if (ELU) v = (v > 0.f) ? v : expm1f(v);
    out[(long long)wid * D + lane] = v;
}

// ---------------- launch ----------------

extern "C" void kernel_launch(void* const* d_in, const int* in_sizes, int n_in,
                              void* d_out, int out_size, void* d_ws, size_t ws_size,
                              hipStream_t stream) {
    const float* feat = (const float*)d_in[0];
    const int*   src  = (const int*)d_in[1];
    const int*   dst  = (const int*)d_in[2];
    const float* W1   = (const float*)d_in[3];
    const float* al1  = (const float*)d_in[4];
    const float* ar1  = (const float*)d_in[5];
    const float* b1   = (const float*)d_in[6];
    const float* W2   = (const float*)d_in[7];
    const float* al2  = (const float*)d_in[8];
    const float* ar2  = (const float*)d_in[9];
    const float* b2   = (const float*)d_in[10];
    float* out = (float*)d_out;

    const int IN = 256, HID = 64, OUT = 64, H1 = 4, H2 = 1;
    const int N = in_sizes[0] / IN;   // 50000
    const int E = in_sizes[1];        // 800000

    // carve workspace
    size_t off = 0;
    auto alloc = [&](size_t bytes) {
        void* p = (char*)d_ws + off;
        off += (bytes + 255) & ~(size_t)255;
        return p;
    };
    int*   deg    = (int*)alloc((size_t)N * 4);
    int*   cursor = (int*)alloc((size_t)N * 4);
    int*   offs   = (int*)alloc((size_t)(N + 1) * 4);
    int*   csr    = (int*)alloc((size_t)E * 4);
    float* h1     = (float*)alloc((size_t)N * H1 * HID * 4);
    float* el1    = (float*)alloc((size_t)N * H1 * 4);
    float* er1    = (float*)alloc((size_t)N * H1 * 4);
    float* x2     = (float*)alloc((size_t)N * H1 * HID * 4);
    float* h2     = (float*)alloc((size_t)N * H2 * OUT * 4);
    float* el2    = (float*)alloc((size_t)N * H2 * 4);
    float* er2    = (float*)alloc((size_t)N * H2 * 4);
    (void)ws_size;

    // zero the atomic counters (ws is re-poisoned before every call)
    hipMemsetAsync(deg, 0, (size_t)N * 4, stream);
    hipMemsetAsync(cursor, 0, (size_t)N * 4, stream);

    // CSR build (shared by both layers)
    deg_kernel<<<(E + 255) / 256, 256, 0, stream>>>(dst, deg, E);
    scan_kernel<<<1, 1024, 0, stream>>>(deg, offs, N);
    fill_kernel<<<(E + 255) / 256, 256, 0, stream>>>(src, dst, offs, cursor, csr, E);

    // ---- layer 1 ----
    gemm_attn<256, 256, 8, 4><<<(N + 7) / 8, 256, 0, stream>>>(feat, W1, al1, ar1,
                                                               h1, el1, er1, N);
    aggr_kernel<4, 64, true><<<(N * H1 + 3) / 4, 256, 0, stream>>>(h1, el1, er1, offs,
                                                                   csr, b1, x2, N);
    // ---- layer 2 ----
    gemm_attn<256, 64, 8, 1><<<(N + 7) / 8, 64, 0, stream>>>(x2, W2, al2, ar2,
                                                             h2, el2, er2, N);
    aggr_kernel<1, 64, false><<<(N * H2 + 3) / 4, 256, 0, stream>>>(h2, el2, er2, offs,
                                                                    csr, b2, out, N);
}

// Round 2
// 682.137 us; speedup vs baseline: 1.2329x; 1.2329x over previous
//
#include <hip/hip_runtime.h>
#include <hip/hip_bf16.h>
#include <math.h>

#define SLOPE 0.2f

// ---------------- CSR build ----------------

__global__ void deg_kernel(const int* __restrict__ dst, int* __restrict__ deg, int E) {
    int i = blockIdx.x * blockDim.x + threadIdx.x;
    if (i < E) atomicAdd(&deg[dst[i]], 1);
}

// single-block exclusive scan over N elements (N ~ 50000)
__global__ __launch_bounds__(1024) void scan_kernel(const int* __restrict__ deg,
                                                    int* __restrict__ offs, int n) {
    __shared__ int sums[1024];
    int t = threadIdx.x;
    int chunk = (n + 1023) >> 10;
    int beg = t * chunk;
    int end = beg + chunk; if (end > n) end = n;
    int s = 0;
    for (int i = beg; i < end && i >= 0; ++i) s += deg[i];
    sums[t] = s;
    __syncthreads();
    for (int off = 1; off < 1024; off <<= 1) {
        int v = (t >= off) ? sums[t - off] : 0;
        __syncthreads();
        sums[t] += v;
        __syncthreads();
    }
    int run = (t == 0) ? 0 : sums[t - 1];
    for (int i = beg; i < end; ++i) { offs[i] = run; run += deg[i]; }
    if (t == 1023) offs[n] = run;   // == E
}

__global__ void fill_kernel(const int* __restrict__ src, const int* __restrict__ dst,
                            const int* __restrict__ offs, int* __restrict__ cursor,
                            int* __restrict__ csr_src, int E) {
    int i = blockIdx.x * blockDim.x + threadIdx.x;
    if (i < E) {
        int d = dst[i];
        int p = atomicAdd(&cursor[d], 1);
        csr_src[offs[d] + p] = src[i];
    }
}

// ---------------- GEMM (+ el/er epilogue) ----------------
// H_out[n, M] = X[n, K] @ W[K, M]; block = M threads, ROWS rows per block.
// Epilogue: el[n,h] = sum_d H[n,h,d]*AL[h,d]; er likewise (wave = head, D=64).
template <int K, int M, int ROWS, int H>
__global__ __launch_bounds__(M) void gemm_attn(const float* __restrict__ X,
                                               const float* __restrict__ W,
                                               const float* __restrict__ AL,
                                               const float* __restrict__ AR,
                                               float* __restrict__ Hout,
                                               float* __restrict__ el,
                                               float* __restrict__ er, int n) {
    __shared__ float xs[ROWS * K];
    const int tid = threadIdx.x;
    const int row0 = blockIdx.x * ROWS;
    for (int idx = tid; idx < ROWS * K; idx += M) {
        int r = idx / K, c = idx - r * K;
        int row = row0 + r;
        xs[idx] = (row < n) ? X[(long long)row * K + c] : 0.f;
    }
    __syncthreads();
    float acc[ROWS];
#pragma unroll
    for (int r = 0; r < ROWS; ++r) acc[r] = 0.f;
    for (int k = 0; k < K; ++k) {
        float wv = W[k * M + tid];
#pragma unroll
        for (int r = 0; r < ROWS; ++r) acc[r] += xs[r * K + k] * wv;
    }
    const int head = tid >> 6;
    const int lane = tid & 63;
    const float alv = AL[head * 64 + lane];
    const float arv = AR[head * 64 + lane];
#pragma unroll
    for (int r = 0; r < ROWS; ++r) {
        int row = row0 + r;
        if (row >= n) break;
        Hout[(long long)row * M + tid] = acc[r];
        float a = acc[r] * alv, b = acc[r] * arv;
#pragma unroll
        for (int s2 = 32; s2 > 0; s2 >>= 1) {
            a += __shfl_xor(a, s2, 64);
            b += __shfl_xor(b, s2, 64);
        }
        if (lane == 0) {
            el[row * H + head] = a;
            er[row * H + head] = b;
        }
    }
}

// ---------------- online-softmax gather-aggregate ----------------
// ONE WAVE PER NODE. lane owns VEC consecutive floats of the [H*D] row
// (VEC = H*D/64). head(lane) = lane*VEC/D; m/l softmax state replicated
// within same-head lane groups.
template <int H, int D, int VEC, bool ELU>
__global__ __launch_bounds__(256) void aggr_kernel(const float* __restrict__ Hf,
                                                   const float* __restrict__ el,
                                                   const float* __restrict__ er,
                                                   const int* __restrict__ offs,
                                                   const int* __restrict__ csr_src,
                                                   const float* __restrict__ bias,
                                                   float* __restrict__ out, int n) {
    const int node = (blockIdx.x * blockDim.x + threadIdx.x) >> 6;
    const int lane = threadIdx.x & 63;
    if (node >= n) return;
    const int head = (lane * VEC) / D;
    const float erv = er[node * H + head];
    const int beg = offs[node], end = offs[node + 1];
    float m = -INFINITY, l = 0.f;
    float acc[VEC];
#pragma unroll
    for (int j = 0; j < VEC; ++j) acc[j] = 0.f;
    for (int i = beg; i < end; ++i) {
        const int s = csr_src[i];
        float e = el[s * H + head] + erv;
        e = (e > 0.f) ? e : SLOPE * e;
        const float mn = fmaxf(m, e);
        const float sc = __expf(m - mn);   // m=-inf first iter -> 0
        const float p = __expf(e - mn);
        const float* hp = Hf + (long long)s * (H * D) + lane * VEC;
        if (VEC == 4) {
            const float4 hv = *(const float4*)hp;
            acc[0] = acc[0] * sc + p * hv.x;
            acc[1] = acc[1] * sc + p * hv.y;
            acc[2] = acc[2] * sc + p * hv.z;
            acc[3] = acc[3] * sc + p * hv.w;
        } else {
            const float hv = *hp;
            acc[0] = acc[0] * sc + p * hv;
        }
        l = l * sc + p;
        m = mn;
    }
    const float inv = (l > 0.f) ? 1.f / l : 0.f;
    float v[VEC];
#pragma unroll
    for (int j = 0; j < VEC; ++j) {
        v[j] = acc[j] * inv + bias[lane * VEC + j];
        if (ELU) v[j] = (v[j] > 0.f) ? v[j] : expm1f(v[j]);
    }
    float* op = out + (long long)node * (H * D) + lane * VEC;
    if (VEC == 4) {
        *(float4*)op = make_float4(v[0], v[1], v[2], v[3]);
    } else {
        *op = v[0];
    }
}

// ---------------- launch ----------------

extern "C" void kernel_launch(void* const* d_in, const int* in_sizes, int n_in,
                              void* d_out, int out_size, void* d_ws, size_t ws_size,
                              hipStream_t stream) {
    const float* feat = (const float*)d_in[0];
    const int*   src  = (const int*)d_in[1];
    const int*   dst  = (const int*)d_in[2];
    const float* W1   = (const float*)d_in[3];
    const float* al1  = (const float*)d_in[4];
    const float* ar1  = (const float*)d_in[5];
    const float* b1   = (const float*)d_in[6];
    const float* W2   = (const float*)d_in[7];
    const float* al2  = (const float*)d_in[8];
    const float* ar2  = (const float*)d_in[9];
    const float* b2   = (const float*)d_in[10];
    float* out = (float*)d_out;

    const int IN = 256, HID = 64, OUT = 64, H1 = 4, H2 = 1;
    const int N = in_sizes[0] / IN;   // 50000
    const int E = in_sizes[1];        // 800000

    size_t off = 0;
    auto alloc = [&](size_t bytes) {
        void* p = (char*)d_ws + off;
        off += (bytes + 255) & ~(size_t)255;
        return p;
    };
    int*   deg    = (int*)alloc((size_t)N * 4);
    int*   cursor = (int*)alloc((size_t)N * 4);
    int*   offs   = (int*)alloc((size_t)(N + 1) * 4);
    int*   csr    = (int*)alloc((size_t)E * 4);
    float* h1     = (float*)alloc((size_t)N * H1 * HID * 4);
    float* el1    = (float*)alloc((size_t)N * H1 * 4);
    float* er1    = (float*)alloc((size_t)N * H1 * 4);
    float* x2     = (float*)alloc((size_t)N * H1 * HID * 4);
    float* h2     = (float*)alloc((size_t)N * H2 * OUT * 4);
    float* el2    = (float*)alloc((size_t)N * H2 * 4);
    float* er2    = (float*)alloc((size_t)N * H2 * 4);
    (void)ws_size;

    hipMemsetAsync(deg, 0, (size_t)N * 4, stream);
    hipMemsetAsync(cursor, 0, (size_t)N * 4, stream);

    deg_kernel<<<(E + 255) / 256, 256, 0, stream>>>(dst, deg, E);
    scan_kernel<<<1, 1024, 0, stream>>>(deg, offs, N);
    fill_kernel<<<(E + 255) / 256, 256, 0, stream>>>(src, dst, offs, cursor, csr, E);

    // ---- layer 1 ----
    gemm_attn<256, 256, 16, 4><<<(N + 15) / 16, 256, 0, stream>>>(feat, W1, al1, ar1,
                                                                  h1, el1, er1, N);
    aggr_kernel<4, 64, 4, true><<<(N + 3) / 4, 256, 0, stream>>>(h1, el1, er1, offs,
                                                                 csr, b1, x2, N);
    // ---- layer 2 ----
    gemm_attn<256, 64, 8, 1><<<(N + 7) / 8, 64, 0, stream>>>(x2, W2, al2, ar2,
                                                             h2, el2, er2, N);
    aggr_kernel<1, 64, 1, false><<<(N + 3) / 4, 256, 0, stream>>>(h2, el2, er2, offs,
                                                                  csr, b2, out, N);
}